// Round 12
// baseline (426.070 us; speedup 1.0000x reference)
//
#include <hip/hip_runtime.h>
#include <hip/hip_bf16.h>

#define N_NODES   100000
#define N_EDGES   1600000
#define F_IN      64
#define HID       64
#define N_CLASSES 45
#define N_GRAPHS  256
#define SB        196         // super-buckets: bucket = dst >> 9 (0..195)
#define NPB       512         // nodes per bucket
#define CAP       9216        // fixed bucket capacity; 9216 = 144*64 (64-divisible)
#define WPB       144         // waves per bucket in k_agge (CAP/64)
#define CHUNK     4096        // edges per scatter workgroup
#define NCHUNK    391         // ceil(N_EDGES / CHUNK)
#define NZB       256         // zero-blocks in the front kernel
#define GEMM_GRID 3125        // N_NODES/32
#define ZLEN4     3204096     // (E1 25.6MB + pool 64KB + E2 25.6MB) / 16

__device__ __forceinline__ float rl_f(float v, int k) {
    return __uint_as_float(__builtin_amdgcn_readlane(__float_as_uint(v), k));
}
__device__ __forceinline__ int rl_i(int v, int k) {
    return __builtin_amdgcn_readlane(v, k);
}
// fp32 <-> bf16 (RNE)
__device__ __forceinline__ unsigned short f2bf(float x) {
    unsigned u = __float_as_uint(x);
    unsigned r = u + 0x7FFFu + ((u >> 16) & 1u);
    return (unsigned short)(r >> 16);
}
__device__ __forceinline__ float bf2f(unsigned short h) {
    return __uint_as_float(((unsigned)h) << 16);
}

// ---------------- front kernel: scatter | zero(E1,pool,E2) | gemm1 ----------------
__global__ __launch_bounds__(256) void k_front(const int* __restrict__ src, const int* __restrict__ dst,
                                               int* __restrict__ bcur, int* __restrict__ binned,
                                               const float* __restrict__ x, const float* __restrict__ W1,
                                               unsigned short* __restrict__ P, float* __restrict__ zbase) {
    int bid = blockIdx.x;
    int t   = threadIdx.x;
    if (bid < NCHUNK) {
        // ---- scatter ----
        __shared__ int stg[CHUNK];
        __shared__ int dbuf[CHUNK];
        __shared__ int h[SB], lbase[SB], gbase[SB], cur[SB];
        __shared__ int ss[256];
        if (t < SB) h[t] = 0;
        __syncthreads();
        int base4 = bid * (CHUNK / 4);
        #pragma unroll
        for (int i = 0; i < CHUNK / 1024; i++) {
            int l4 = i * 256 + t;
            int e4 = base4 + l4;
            if (e4 < N_EDGES / 4) {
                int4 d = ((const int4*)dst)[e4];
                ((int4*)dbuf)[l4] = d;
                atomicAdd(&h[d.x >> 9], 1);
                atomicAdd(&h[d.y >> 9], 1);
                atomicAdd(&h[d.z >> 9], 1);
                atomicAdd(&h[d.w >> 9], 1);
            }
        }
        __syncthreads();
        ss[t] = (t < SB) ? h[t] : 0;
        __syncthreads();
        for (int o = 1; o < 256; o <<= 1) {
            int v = (t >= o) ? ss[t - o] : 0;
            __syncthreads();
            if (t >= o) ss[t] += v;
            __syncthreads();
        }
        if (t < SB) {
            int ex = ss[t] - h[t];
            lbase[t] = ex;
            cur[t]   = ex;
            gbase[t] = t * CAP + atomicAdd(&bcur[t], h[t]);
        }
        __syncthreads();
        #pragma unroll
        for (int i = 0; i < CHUNK / 1024; i++) {
            int l4 = i * 256 + t;
            int e4 = base4 + l4;
            if (e4 < N_EDGES / 4) {
                int4 s4 = ((const int4*)src)[e4];
                int4 d  = ((int4*)dbuf)[l4];
                int q;
                q = atomicAdd(&cur[d.x >> 9], 1); stg[q] = s4.x | ((d.x & 511) << 17);
                q = atomicAdd(&cur[d.y >> 9], 1); stg[q] = s4.y | ((d.y & 511) << 17);
                q = atomicAdd(&cur[d.z >> 9], 1); stg[q] = s4.z | ((d.z & 511) << 17);
                q = atomicAdd(&cur[d.w >> 9], 1); stg[q] = s4.w | ((d.w & 511) << 17);
            }
        }
        __syncthreads();
        int wv = t >> 6, lane = t & 63;
        for (int b = wv; b < SB; b += 4) {
            int n = h[b], lb = lbase[b], gb = gbase[b];
            for (int i = lane; i < n; i += 64)
                binned[gb + i] = stg[lb + i];
        }
    } else if (bid < NCHUNK + NZB) {
        // ---- zero E1 | pool | E2 ----
        float4 z = make_float4(0.f, 0.f, 0.f, 0.f);
        float4* zp = (float4*)zbase;
        int zb = bid - NCHUNK;
        for (long i = (long)zb * 256 + t; i < (long)ZLEN4; i += (long)NZB * 256)
            zp[i] = z;
    } else {
        // ---- gemm1: H1 = x @ W1 (bf16) ----
        int gbid = bid - NCHUNK - NZB;
        int lane = t & 63;
        int wv   = t >> 6;
        int base = gbid * 32 + wv * 8;
        float xr[8], acc[8];
        #pragma unroll
        for (int r = 0; r < 8; r++) {
            xr[r]  = x[(size_t)(base + r) * 64 + lane];
            acc[r] = 0.f;
        }
        for (int kb = 0; kb < 64; kb += 8) {
            float wb[8];
            #pragma unroll
            for (int j = 0; j < 8; j++) wb[j] = W1[(kb + j) * 64 + lane];
            #pragma unroll
            for (int j = 0; j < 8; j++) {
                #pragma unroll
                for (int r = 0; r < 8; r++)
                    acc[r] = fmaf(rl_f(xr[r], kb + j), wb[j], acc[r]);
            }
        }
        #pragma unroll
        for (int r = 0; r < 8; r++)
            P[(size_t)(base + r) * 64 + lane] = f2bf(acc[r]);
    }
}

// ---------------- per-bucket: degrees -> dinv/dinv2 + node-sorted csr fill ----------------
__global__ __launch_bounds__(256) void k_bcsr(const int* __restrict__ binned, const int* __restrict__ bcur,
                                              float* __restrict__ dinv, float* __restrict__ dinv2,
                                              int* __restrict__ csr) {
    __shared__ int h[NPB];
    __shared__ int ts[256];
    int t = threadIdx.x;
    int b = blockIdx.x;
    int nb0  = b << 9;
    int ebeg = b * CAP;
    int ecnt = bcur[b]; if (ecnt > CAP) ecnt = CAP;
    h[t] = 0; h[t + 256] = 0;
    __syncthreads();
    for (int i = t; i < ecnt; i += 256)
        atomicAdd(&h[binned[ebeg + i] >> 17], 1);
    __syncthreads();
    int c0 = h[t * 2], c1 = h[t * 2 + 1];
    int tot = c0 + c1;
    ts[t] = tot;
    __syncthreads();
    for (int o = 1; o < 256; o <<= 1) {
        int v = (t >= o) ? ts[t - o] : 0;
        __syncthreads();
        if (t >= o) ts[t] += v;
        __syncthreads();
    }
    int ex = ts[t] - tot + ebeg;
    int n0 = nb0 + t * 2;
    int e0 = ex, e1 = ex + c0;
    if (n0 < N_NODES) {
        float i0 = 1.0f / (float)(c0 + 1);       // +1 self loop
        float i1 = 1.0f / (float)(c1 + 1);
        dinv2[n0]     = i0;  dinv2[n0 + 1] = i1;
        dinv[n0]      = sqrtf(i0);
        dinv[n0 + 1]  = sqrtf(i1);
    }
    __syncthreads();
    h[t * 2] = e0; h[t * 2 + 1] = e1;            // per-node write cursors
    __syncthreads();
    for (int i = t; i < ecnt; i += 256) {
        int p = binned[ebeg + i];
        int q = atomicAdd(&h[p >> 17], 1);
        csr[q] = p;                               // keep src | dstLow<<17
    }
}

// ---------------- GEMM layers 2/3 ----------------
// xin = relu(E[n] + bprev + Hprev[n]*dinv2[n]);  Hnew = xin @ W  (bf16, in-place in P)
// POOLI (layer 3): pool[batch[n]] += bcurr + Hnew[n]*dinv2[n]
template<bool POOLI>
__global__ __launch_bounds__(256) void k_gemm(const float* __restrict__ E,
                                              unsigned short* P,            // aliased in/out (row-private)
                                              const float* __restrict__ W,
                                              const float* __restrict__ bprev,
                                              const float* __restrict__ bcurr,
                                              const float* __restrict__ dinv2,
                                              const int* __restrict__ batch,
                                              float* __restrict__ pool) {
    int lane = threadIdx.x & 63;
    int wv   = threadIdx.x >> 6;
    int base = blockIdx.x * 32 + wv * 8;           // grid exact (3125*32)
    float bp = bprev[lane];
    float xr[8], acc[8];
    #pragma unroll
    for (int r = 0; r < 8; r++) {
        int n = base + r;
        float hp = bf2f(P[(size_t)n * 64 + lane]);
        float a  = E[(size_t)n * 64 + lane] + fmaf(hp, dinv2[n], bp);
        xr[r]  = fmaxf(a, 0.f);
        acc[r] = 0.f;
    }
    for (int kb = 0; kb < 64; kb += 8) {
        float wb[8];
        #pragma unroll
        for (int j = 0; j < 8; j++) wb[j] = W[(kb + j) * 64 + lane];
        #pragma unroll
        for (int j = 0; j < 8; j++) {
            #pragma unroll
            for (int r = 0; r < 8; r++)
                acc[r] = fmaf(rl_f(xr[r], kb + j), wb[j], acc[r]);
        }
    }
    #pragma unroll
    for (int r = 0; r < 8; r++)
        P[(size_t)(base + r) * 64 + lane] = f2bf(acc[r]);
    if (POOLI) {
        float bv = bcurr[lane];
        float d2[8];
        #pragma unroll
        for (int r = 0; r < 8; r++) d2[r] = dinv2[base + r];
        int g0 = batch[base], g7 = batch[base + 7];
        if (g0 == g7) {
            float s = 0.f;
            #pragma unroll
            for (int r = 0; r < 8; r++) s += fmaf(acc[r], d2[r], bv);
            atomicAdd(&pool[g0 * 64 + lane], s);
        } else {
            #pragma unroll
            for (int r = 0; r < 8; r++) {
                int g = batch[base + r];
                atomicAdd(&pool[g * 64 + lane], fmaf(acc[r], d2[r], bv));
            }
        }
    }
}

// ---------------- Edge-parallel aggregation: 8-rows-per-instruction staging ----------------
// Wave owns 64 csr slots. Stage: 8 global int4 loads (each lane 16B of a row,
// 8 lanes/row -> 8 rows/instruction) into the wave's 8KB LDS slab; per-lane
// row index via ds_bpermute of the src vector. Consume: ds_read_u16 + fma,
// run boundaries from ballot mask; flush = atomicAdd (Out pre-zeroed).
// POOLEP: flush into pool[batch[dst]] instead (layer 3).
template<bool POOLEP>
__global__ __launch_bounds__(256, 8) void k_agge(const unsigned short* __restrict__ Hbuf,
                                                 const int* __restrict__ csr,
                                                 const int* __restrict__ bcur,
                                                 const float* __restrict__ dinv,
                                                 const int* __restrict__ batch,
                                                 float* __restrict__ Out) {
    __shared__ unsigned short rows[4][2][32 * 64];   // [wave][chunk][32 rows x 64 feat] = 32 KB
    int wv   = threadIdx.x >> 6;
    int lane = threadIdx.x & 63;
    int wid  = blockIdx.x * 4 + wv;                // 0 .. SB*WPB-1 (grid exact)
    int b    = wid / WPB;
    int lw   = wid - b * WPB;
    int used = bcur[b]; if (used > CAP) used = CAP;
    int e0   = lw * 64;
    int rem  = used - e0;
    if (rem <= 0) return;
    if (rem > 64) rem = 64;
    int base = b * CAP + e0;

    int p = 0;
    float cv = 0.f;
    if (lane < rem) {
        p  = csr[base + lane];                     // coalesced 256B
        cv = dinv[p & 0x1FFFF];                    // lane-parallel gather, L2-hot
    }
    int sv = p & 0x1FFFF;                          // lanes >= rem: sv = 0 (safe row)
    int dv = p >> 17;                              // dstLow (9b)
    if (rem < 64) {                                // pad tail lanes into last run (coef 0)
        int dlast = rl_i(dv, rem - 1);
        if (lane >= rem) dv = dlast;
    }
    int dup = __shfl_up(dv, 1);
    unsigned long long bm = __ballot(lane > 0 && dv != dup);

    // ---- stage 64 rows: 8 int4 gathers, 8 rows each ----
    int sub = lane & 7;                            // 16B piece within row
    int4* slab0 = (int4*)&rows[wv][0][0];
    int4* slab1 = (int4*)&rows[wv][1][0];
    int4 v0[4], v1[4];
    #pragma unroll
    for (int i = 0; i < 4; i++) {
        int ridx = i * 8 + (lane >> 3);
        int srow = __builtin_amdgcn_ds_bpermute(ridx << 2, sv);
        v0[i] = ((const int4*)(Hbuf + (size_t)srow * 64))[sub];
    }
    #pragma unroll
    for (int i = 0; i < 4; i++) {
        int ridx = 32 + i * 8 + (lane >> 3);
        int srow = __builtin_amdgcn_ds_bpermute(ridx << 2, sv);
        v1[i] = ((const int4*)(Hbuf + (size_t)srow * 64))[sub];
    }
    #pragma unroll
    for (int i = 0; i < 4; i++) slab0[i * 64 + lane] = v0[i];
    #pragma unroll
    for (int i = 0; i < 4; i++) slab1[i * 64 + lane] = v1[i];

    auto flush = [&](int dl, float a) {
        int dst = (b << 9) + dl;
        if (dst < N_NODES) {
            float val = dinv[dst] * a;             // uniform load
            if (POOLEP) {
                int g = batch[dst];                // uniform load
                atomicAdd(&Out[g * 64 + lane], val);
            } else {
                atomicAdd(&Out[(size_t)dst * 64 + lane], val);
            }
        }
    };

    // ---- consume 64 edges from LDS ----
    int   curd = rl_i(dv, 0);
    float acc  = 0.f;
    const unsigned short* rp0 = &rows[wv][0][0];
    const unsigned short* rp1 = &rows[wv][1][0];
    #pragma unroll
    for (int e = 0; e < 32; e++) {
        if ((bm >> e) & 1ull) { flush(curd, acc); acc = 0.f; curd = rl_i(dv, e); }
        acc = fmaf(bf2f(rp0[e * 64 + lane]), rl_f(cv, e), acc);
    }
    #pragma unroll
    for (int i = 0; i < 32; i++) {
        int e = 32 + i;
        if ((bm >> e) & 1ull) { flush(curd, acc); acc = 0.f; curd = rl_i(dv, e); }
        acc = fmaf(bf2f(rp1[i * 64 + lane]), rl_f(cv, e), acc);
    }
    flush(curd, acc);
}

// ---------------- mean + classifier ----------------
__device__ __forceinline__ int lbound(const int* __restrict__ a, int n, int v) {
    int lo = 0, hi = n;
    while (lo < hi) { int m = (lo + hi) >> 1; if (a[m] < v) lo = m + 1; else hi = m; }
    return lo;
}

__global__ __launch_bounds__(64) void k_cls(const float* __restrict__ pool, const int* __restrict__ batch,
                                            const float* __restrict__ Wl, const float* __restrict__ bl,
                                            float* __restrict__ out) {
    __shared__ float pm[64];
    __shared__ int bounds[2];
    int g = blockIdx.x;
    int t = threadIdx.x;
    if (t < 2) bounds[t] = lbound(batch, N_NODES, g + t);
    __syncthreads();
    float cnt = (float)(bounds[1] - bounds[0]);
    pm[t] = pool[g * 64 + t] / fmaxf(cnt, 1.0f);
    __syncthreads();
    if (t < N_CLASSES) {
        float o = bl[t];
        #pragma unroll
        for (int k = 0; k < HID; k++) o = fmaf(pm[k], Wl[k * N_CLASSES + t], o);
        out[g * N_CLASSES + t] = o;
    }
}

// ---------------- launch ----------------

extern "C" void kernel_launch(void* const* d_in, const int* in_sizes, int n_in,
                              void* d_out, int out_size, void* d_ws, size_t ws_size,
                              hipStream_t stream) {
    const float* x     = (const float*)d_in[0];
    const int*   eidx  = (const int*)  d_in[1];
    const int*   batch = (const int*)  d_in[2];
    const float* W1 = (const float*)d_in[3];
    const float* b1 = (const float*)d_in[4];
    const float* W2 = (const float*)d_in[5];
    const float* b2 = (const float*)d_in[6];
    const float* W3 = (const float*)d_in[7];
    const float* b3 = (const float*)d_in[8];
    const float* Wl = (const float*)d_in[9];
    const float* bl = (const float*)d_in[10];
    const int* src = eidx;
    const int* dst = eidx + N_EDGES;

    char* p = (char*)d_ws;
    auto alloc = [&](size_t bytes) -> void* {
        void* r = (void*)p;
        p += (bytes + 255) & ~(size_t)255;
        return r;
    };
    float* dinv  = (float*)alloc((size_t)N_NODES * 4);
    float* dinv2 = (float*)alloc((size_t)N_NODES * 4);
    int*   csr   = (int*)  alloc((size_t)SB * CAP * 4);
    unsigned short* P = (unsigned short*)alloc((size_t)N_NODES * 64 * 2);  // bf16 H
    float* E1    = (float*)alloc((size_t)N_NODES * 64 * 4);   // edge sums L1 (zeroed span start)
    float* pool  = (float*)alloc((size_t)N_GRAPHS * 64 * 4);  // contiguous after E1
    float* E2    = (float*)alloc((size_t)N_NODES * 64 * 4);   // contiguous after pool
    int*   bcur  = (int*)  alloc((size_t)SB * 4);
    int*   binned = (int*) alloc((size_t)SB * CAP * 4);

    const int agge_grid  = SB * WPB / 4;           // 7056, exact
    const int front_grid = NCHUNK + NZB + GEMM_GRID;

    // ---- front: scatter | zero(E1,pool,E2) | gemm1 (all independent) ----
    hipMemsetAsync(bcur, 0, (size_t)SB * 4, stream);
    k_front<<<front_grid, 256, 0, stream>>>(src, dst, bcur, binned, x, W1, P, E1);
    k_bcsr <<<SB, 256, 0, stream>>>(binned, bcur, dinv, dinv2, csr);

    // layer 1 edges: H1 gathers -> E1
    k_agge<false><<<agge_grid, 256, 0, stream>>>(P, csr, bcur, dinv, batch, E1);
    // layer 2: relu(E1 + b1 + H1*dinv2) @ W2 -> H2 (in-place in P); edges -> E2
    k_gemm<false><<<GEMM_GRID, 256, 0, stream>>>(E1, P, W2, b1, nullptr, dinv2, batch, nullptr);
    k_agge<false><<<agge_grid, 256, 0, stream>>>(P, csr, bcur, dinv, batch, E2);
    // layer 3: relu(E2 + b2 + H2*dinv2) @ W3 -> H3; self terms -> pool; edges -> pool
    k_gemm<true ><<<GEMM_GRID, 256, 0, stream>>>(E2, P, W3, b2, b3, dinv2, batch, pool);
    k_agge<true ><<<agge_grid, 256, 0, stream>>>(P, csr, bcur, dinv, batch, pool);

    // mean + classifier
    k_cls<<<N_GRAPHS, 64, 0, stream>>>(pool, batch, Wl, bl, (float*)d_out);
}

// Round 13
// 388.185 us; speedup vs baseline: 1.0976x; 1.0976x over previous
//
#include <hip/hip_runtime.h>
#include <hip/hip_bf16.h>

#define N_NODES   100000
#define N_EDGES   1600000
#define F_IN      64
#define HID       64
#define N_CLASSES 45
#define N_GRAPHS  256
#define SB        392         // super-buckets: bucket = dst >> 8 (0..391)
#define NPB       256         // nodes per bucket
#define CAP       4608        // fixed bucket capacity; 4608 = 72*64 (mean 4082, sigma 64 -> +8s)
#define WPB       72          // waves per bucket in k_agge (CAP/64)
#define CHUNK     4096        // edges per scatter workgroup
#define NCHUNK    391         // ceil(N_EDGES / CHUNK)
#define NZB       256         // zero-blocks in the front kernel
#define GEMM_GRID 3125        // N_NODES/32
#define ZLEN4     3204096     // (E1 25.6MB + pool 64KB + E2 25.6MB) / 16

__device__ __forceinline__ float rl_f(float v, int k) {
    return __uint_as_float(__builtin_amdgcn_readlane(__float_as_uint(v), k));
}
__device__ __forceinline__ int rl_i(int v, int k) {
    return __builtin_amdgcn_readlane(v, k);
}
// fp32 <-> bf16 (RNE)
__device__ __forceinline__ unsigned short f2bf(float x) {
    unsigned u = __float_as_uint(x);
    unsigned r = u + 0x7FFFu + ((u >> 16) & 1u);
    return (unsigned short)(r >> 16);
}
__device__ __forceinline__ float bf2f(unsigned short h) {
    return __uint_as_float(((unsigned)h) << 16);
}

// ---------------- front kernel: scatter | zero(E1,pool,E2) | gemm1 ----------------
// payload: src(17b) | dstLow(8b)<<17
__global__ __launch_bounds__(256) void k_front(const int* __restrict__ src, const int* __restrict__ dst,
                                               int* __restrict__ bcur, int* __restrict__ binned,
                                               const float* __restrict__ x, const float* __restrict__ W1,
                                               unsigned short* __restrict__ P, float* __restrict__ zbase) {
    int bid = blockIdx.x;
    int t   = threadIdx.x;
    if (bid < NCHUNK) {
        // ---- scatter (bucket multisplit) ----
        __shared__ int stg[CHUNK];
        __shared__ int dbuf[CHUNK];
        __shared__ int h[512], lb[512], gb[512], cur[512];
        __shared__ int ps[256];
        h[t] = 0; h[t + 256] = 0;
        __syncthreads();
        int base4 = bid * (CHUNK / 4);
        #pragma unroll
        for (int i = 0; i < CHUNK / 1024; i++) {
            int l4 = i * 256 + t;
            int e4 = base4 + l4;
            if (e4 < N_EDGES / 4) {
                int4 d = ((const int4*)dst)[e4];
                ((int4*)dbuf)[l4] = d;
                atomicAdd(&h[d.x >> 8], 1);
                atomicAdd(&h[d.y >> 8], 1);
                atomicAdd(&h[d.z >> 8], 1);
                atomicAdd(&h[d.w >> 8], 1);
            }
        }
        __syncthreads();
        // pair-scan over 512 bucket slots with 256 threads
        int a0 = h[2 * t], a1 = h[2 * t + 1];
        ps[t] = a0 + a1;
        __syncthreads();
        for (int o = 1; o < 256; o <<= 1) {
            int v = (t >= o) ? ps[t - o] : 0;
            __syncthreads();
            if (t >= o) ps[t] += v;
            __syncthreads();
        }
        int pex = ps[t] - (a0 + a1);               // exclusive over pairs
        int e0 = pex, e1 = pex + a0;
        lb[2 * t] = e0;  lb[2 * t + 1] = e1;
        cur[2 * t] = e0; cur[2 * t + 1] = e1;
        if (2 * t < SB)     gb[2 * t]     = (2 * t) * CAP     + atomicAdd(&bcur[2 * t], a0);
        if (2 * t + 1 < SB) gb[2 * t + 1] = (2 * t + 1) * CAP + atomicAdd(&bcur[2 * t + 1], a1);
        __syncthreads();
        #pragma unroll
        for (int i = 0; i < CHUNK / 1024; i++) {
            int l4 = i * 256 + t;
            int e4 = base4 + l4;
            if (e4 < N_EDGES / 4) {
                int4 s4 = ((const int4*)src)[e4];
                int4 d  = ((int4*)dbuf)[l4];
                int q;
                q = atomicAdd(&cur[d.x >> 8], 1); stg[q] = s4.x | ((d.x & 255) << 17);
                q = atomicAdd(&cur[d.y >> 8], 1); stg[q] = s4.y | ((d.y & 255) << 17);
                q = atomicAdd(&cur[d.z >> 8], 1); stg[q] = s4.z | ((d.z & 255) << 17);
                q = atomicAdd(&cur[d.w >> 8], 1); stg[q] = s4.w | ((d.w & 255) << 17);
            }
        }
        __syncthreads();
        int wv = t >> 6, lane = t & 63;
        for (int b = wv; b < SB; b += 4) {
            int n = h[b], l0 = lb[b], g0 = gb[b];
            for (int i = lane; i < n; i += 64)
                binned[g0 + i] = stg[l0 + i];
        }
    } else if (bid < NCHUNK + NZB) {
        // ---- zero E1 | pool | E2 ----
        float4 z = make_float4(0.f, 0.f, 0.f, 0.f);
        float4* zp = (float4*)zbase;
        int zb = bid - NCHUNK;
        for (long i = (long)zb * 256 + t; i < (long)ZLEN4; i += (long)NZB * 256)
            zp[i] = z;
    } else {
        // ---- gemm1: H1 = x @ W1 (bf16) ----
        int gbid = bid - NCHUNK - NZB;
        int lane = t & 63;
        int wv   = t >> 6;
        int base = gbid * 32 + wv * 8;
        float xr[8], acc[8];
        #pragma unroll
        for (int r = 0; r < 8; r++) {
            xr[r]  = x[(size_t)(base + r) * 64 + lane];
            acc[r] = 0.f;
        }
        for (int kb = 0; kb < 64; kb += 8) {
            float wb[8];
            #pragma unroll
            for (int j = 0; j < 8; j++) wb[j] = W1[(kb + j) * 64 + lane];
            #pragma unroll
            for (int j = 0; j < 8; j++) {
                #pragma unroll
                for (int r = 0; r < 8; r++)
                    acc[r] = fmaf(rl_f(xr[r], kb + j), wb[j], acc[r]);
            }
        }
        #pragma unroll
        for (int r = 0; r < 8; r++)
            P[(size_t)(base + r) * 64 + lane] = f2bf(acc[r]);
    }
}

// ---------------- per-bucket: degrees -> dinv/dinv2 + node-sorted csr fill ----------------
__global__ __launch_bounds__(256) void k_bcsr(const int* __restrict__ binned, const int* __restrict__ bcur,
                                              float* __restrict__ dinv, float* __restrict__ dinv2,
                                              int* __restrict__ csr) {
    __shared__ int h[NPB];
    __shared__ int ts[NPB];
    int t = threadIdx.x;
    int b = blockIdx.x;
    int nb0  = b << 8;
    int ebeg = b * CAP;
    int ecnt = bcur[b]; if (ecnt > CAP) ecnt = CAP;
    h[t] = 0;
    __syncthreads();
    for (int i = t; i < ecnt; i += 256)
        atomicAdd(&h[binned[ebeg + i] >> 17], 1);
    __syncthreads();
    int c = h[t];
    ts[t] = c;
    __syncthreads();
    for (int o = 1; o < 256; o <<= 1) {
        int v = (t >= o) ? ts[t - o] : 0;
        __syncthreads();
        if (t >= o) ts[t] += v;
        __syncthreads();
    }
    int excl = ts[t] - c + ebeg;
    int n = nb0 + t;
    if (n < N_NODES) {
        float inv = 1.0f / (float)(c + 1);         // +1 self loop
        dinv2[n] = inv;
        dinv[n]  = sqrtf(inv);
    }
    __syncthreads();
    h[t] = excl;                                   // per-node write cursor
    __syncthreads();
    for (int i = t; i < ecnt; i += 256) {
        int p = binned[ebeg + i];
        int q = atomicAdd(&h[p >> 17], 1);
        csr[q] = p;                                // keep src | dstLow<<17
    }
}

// ---------------- GEMM layers 2/3 ----------------
// xin = relu(E[n] + bprev + Hprev[n]*dinv2[n]);  Hnew = xin @ W  (bf16, in-place in P)
// POOLI (layer 3): pool[batch[n]] += bcurr + Hnew[n]*dinv2[n]
template<bool POOLI>
__global__ __launch_bounds__(256) void k_gemm(const float* __restrict__ E,
                                              unsigned short* P,            // aliased in/out (row-private)
                                              const float* __restrict__ W,
                                              const float* __restrict__ bprev,
                                              const float* __restrict__ bcurr,
                                              const float* __restrict__ dinv2,
                                              const int* __restrict__ batch,
                                              float* __restrict__ pool) {
    int lane = threadIdx.x & 63;
    int wv   = threadIdx.x >> 6;
    int base = blockIdx.x * 32 + wv * 8;           // grid exact (3125*32)
    float bp = bprev[lane];
    float xr[8], acc[8];
    #pragma unroll
    for (int r = 0; r < 8; r++) {
        int n = base + r;
        float hp = bf2f(P[(size_t)n * 64 + lane]);
        float a  = E[(size_t)n * 64 + lane] + fmaf(hp, dinv2[n], bp);
        xr[r]  = fmaxf(a, 0.f);
        acc[r] = 0.f;
    }
    for (int kb = 0; kb < 64; kb += 8) {
        float wb[8];
        #pragma unroll
        for (int j = 0; j < 8; j++) wb[j] = W[(kb + j) * 64 + lane];
        #pragma unroll
        for (int j = 0; j < 8; j++) {
            #pragma unroll
            for (int r = 0; r < 8; r++)
                acc[r] = fmaf(rl_f(xr[r], kb + j), wb[j], acc[r]);
        }
    }
    #pragma unroll
    for (int r = 0; r < 8; r++)
        P[(size_t)(base + r) * 64 + lane] = f2bf(acc[r]);
    if (POOLI) {
        float bv = bcurr[lane];
        float d2[8];
        #pragma unroll
        for (int r = 0; r < 8; r++) d2[r] = dinv2[base + r];
        int g0 = batch[base], g7 = batch[base + 7];
        if (g0 == g7) {
            float s = 0.f;
            #pragma unroll
            for (int r = 0; r < 8; r++) s += fmaf(acc[r], d2[r], bv);
            atomicAdd(&pool[g0 * 64 + lane], s);
        } else {
            #pragma unroll
            for (int r = 0; r < 8; r++) {
                int g = batch[base + r];
                atomicAdd(&pool[g * 64 + lane], fmaf(acc[r], d2[r], bv));
            }
        }
    }
}

// ---------------- Edge-parallel aggregation (bf16 gather; R10 loop) ----------------
// Wave owns 64 csr slots (node-sorted runs within one bucket).
// For each dst-run: Out[dst] += dinv[dst] * sum(dinv[src]*H[src])  (atomic; Out pre-zeroed)
// POOLEP: flush into pool[batch[dst]] instead (layer 3).
template<bool POOLEP>
__global__ __launch_bounds__(256, 8) void k_agge(const unsigned short* __restrict__ Hbuf,
                                                 const int* __restrict__ csr,
                                                 const int* __restrict__ bcur,
                                                 const float* __restrict__ dinv,
                                                 const int* __restrict__ batch,
                                                 float* __restrict__ Out) {
    int wv   = threadIdx.x >> 6;
    int lane = threadIdx.x & 63;
    int wid  = blockIdx.x * 4 + wv;                // 0 .. SB*WPB-1 (grid exact)
    int b    = wid / WPB;
    int lw   = wid - b * WPB;
    int used = bcur[b]; if (used > CAP) used = CAP;
    int e0   = lw * 64;
    int rem  = used - e0;
    if (rem <= 0) return;
    if (rem > 64) rem = 64;
    int base = b * CAP + e0;

    int p = 0;
    float cv = 0.f;
    if (lane < rem) {
        p  = csr[base + lane];                     // coalesced 256B
        cv = dinv[p & 0x1FFFF];                    // lane-parallel gather, L2-hot
    }
    int sv = p & 0x1FFFF;
    int dv = p >> 17;                              // dstLow (8b)

    auto flush = [&](int dl, float a) {
        int dst = (b << 8) + dl;
        if (dst < N_NODES) {
            float val = dinv[dst] * a;             // uniform load
            if (POOLEP) {
                int g = batch[dst];                // uniform load
                atomicAdd(&Out[g * 64 + lane], val);
            } else {
                atomicAdd(&Out[(size_t)dst * 64 + lane], val);
            }
        }
    };

    int dprev = rl_i(dv, 0);
    float acc = 0.f;
    int j = 0;
    for (; j + 8 <= rem; j += 8) {
        int   s0 = rl_i(sv, j),     s1 = rl_i(sv, j + 1);
        int   s2 = rl_i(sv, j + 2), s3 = rl_i(sv, j + 3);
        int   s4 = rl_i(sv, j + 4), s5 = rl_i(sv, j + 5);
        int   s6 = rl_i(sv, j + 6), s7 = rl_i(sv, j + 7);
        float c0 = rl_f(cv, j),     c1 = rl_f(cv, j + 1);
        float c2 = rl_f(cv, j + 2), c3 = rl_f(cv, j + 3);
        float c4 = rl_f(cv, j + 4), c5 = rl_f(cv, j + 5);
        float c6 = rl_f(cv, j + 6), c7 = rl_f(cv, j + 7);
        int   d0 = rl_i(dv, j),     d1 = rl_i(dv, j + 1);
        int   d2 = rl_i(dv, j + 2), d3 = rl_i(dv, j + 3);
        int   d4 = rl_i(dv, j + 4), d5 = rl_i(dv, j + 5);
        int   d6 = rl_i(dv, j + 6), d7 = rl_i(dv, j + 7);
        unsigned short u0 = Hbuf[(size_t)s0 * 64 + lane];   // 8 gathers in flight
        unsigned short u1 = Hbuf[(size_t)s1 * 64 + lane];
        unsigned short u2 = Hbuf[(size_t)s2 * 64 + lane];
        unsigned short u3 = Hbuf[(size_t)s3 * 64 + lane];
        unsigned short u4 = Hbuf[(size_t)s4 * 64 + lane];
        unsigned short u5 = Hbuf[(size_t)s5 * 64 + lane];
        unsigned short u6 = Hbuf[(size_t)s6 * 64 + lane];
        unsigned short u7 = Hbuf[(size_t)s7 * 64 + lane];
        if (d0 != dprev) { flush(dprev, acc); acc = 0.f; dprev = d0; }
        acc = fmaf(bf2f(u0), c0, acc);
        if (d1 != dprev) { flush(dprev, acc); acc = 0.f; dprev = d1; }
        acc = fmaf(bf2f(u1), c1, acc);
        if (d2 != dprev) { flush(dprev, acc); acc = 0.f; dprev = d2; }
        acc = fmaf(bf2f(u2), c2, acc);
        if (d3 != dprev) { flush(dprev, acc); acc = 0.f; dprev = d3; }
        acc = fmaf(bf2f(u3), c3, acc);
        if (d4 != dprev) { flush(dprev, acc); acc = 0.f; dprev = d4; }
        acc = fmaf(bf2f(u4), c4, acc);
        if (d5 != dprev) { flush(dprev, acc); acc = 0.f; dprev = d5; }
        acc = fmaf(bf2f(u5), c5, acc);
        if (d6 != dprev) { flush(dprev, acc); acc = 0.f; dprev = d6; }
        acc = fmaf(bf2f(u6), c6, acc);
        if (d7 != dprev) { flush(dprev, acc); acc = 0.f; dprev = d7; }
        acc = fmaf(bf2f(u7), c7, acc);
    }
    for (; j < rem; j++) {
        int   s0 = rl_i(sv, j);
        float c0 = rl_f(cv, j);
        int   d0 = rl_i(dv, j);
        unsigned short u0 = Hbuf[(size_t)s0 * 64 + lane];
        if (d0 != dprev) { flush(dprev, acc); acc = 0.f; dprev = d0; }
        acc = fmaf(bf2f(u0), c0, acc);
    }
    flush(dprev, acc);
}

// ---------------- mean + classifier ----------------
__device__ __forceinline__ int lbound(const int* __restrict__ a, int n, int v) {
    int lo = 0, hi = n;
    while (lo < hi) { int m = (lo + hi) >> 1; if (a[m] < v) lo = m + 1; else hi = m; }
    return lo;
}

__global__ __launch_bounds__(64) void k_cls(const float* __restrict__ pool, const int* __restrict__ batch,
                                            const float* __restrict__ Wl, const float* __restrict__ bl,
                                            float* __restrict__ out) {
    __shared__ float pm[64];
    __shared__ int bounds[2];
    int g = blockIdx.x;
    int t = threadIdx.x;
    if (t < 2) bounds[t] = lbound(batch, N_NODES, g + t);
    __syncthreads();
    float cnt = (float)(bounds[1] - bounds[0]);
    pm[t] = pool[g * 64 + t] / fmaxf(cnt, 1.0f);
    __syncthreads();
    if (t < N_CLASSES) {
        float o = bl[t];
        #pragma unroll
        for (int k = 0; k < HID; k++) o = fmaf(pm[k], Wl[k * N_CLASSES + t], o);
        out[g * N_CLASSES + t] = o;
    }
}

// ---------------- launch ----------------

extern "C" void kernel_launch(void* const* d_in, const int* in_sizes, int n_in,
                              void* d_out, int out_size, void* d_ws, size_t ws_size,
                              hipStream_t stream) {
    const float* x     = (const float*)d_in[0];
    const int*   eidx  = (const int*)  d_in[1];
    const int*   batch = (const int*)  d_in[2];
    const float* W1 = (const float*)d_in[3];
    const float* b1 = (const float*)d_in[4];
    const float* W2 = (const float*)d_in[5];
    const float* b2 = (const float*)d_in[6];
    const float* W3 = (const float*)d_in[7];
    const float* b3 = (const float*)d_in[8];
    const float* Wl = (const float*)d_in[9];
    const float* bl = (const float*)d_in[10];
    const int* src = eidx;
    const int* dst = eidx + N_EDGES;

    char* p = (char*)d_ws;
    auto alloc = [&](size_t bytes) -> void* {
        void* r = (void*)p;
        p += (bytes + 255) & ~(size_t)255;
        return r;
    };
    float* dinv  = (float*)alloc((size_t)N_NODES * 4);
    float* dinv2 = (float*)alloc((size_t)N_NODES * 4);
    int*   csr   = (int*)  alloc((size_t)SB * CAP * 4);
    unsigned short* P = (unsigned short*)alloc((size_t)N_NODES * 64 * 2);  // bf16 H
    float* E1    = (float*)alloc((size_t)N_NODES * 64 * 4);   // edge sums L1 (zeroed span start)
    float* pool  = (float*)alloc((size_t)N_GRAPHS * 64 * 4);  // contiguous after E1
    float* E2    = (float*)alloc((size_t)N_NODES * 64 * 4);   // contiguous after pool
    int*   bcur  = (int*)  alloc((size_t)SB * 4);
    int*   binned = (int*) alloc((size_t)SB * CAP * 4);

    const int agge_grid  = SB * WPB / 4;           // 7056, exact
    const int front_grid = NCHUNK + NZB + GEMM_GRID;

    // ---- front: scatter | zero(E1,pool,E2) | gemm1 (all independent) ----
    hipMemsetAsync(bcur, 0, (size_t)SB * 4, stream);
    k_front<<<front_grid, 256, 0, stream>>>(src, dst, bcur, binned, x, W1, P, E1);
    k_bcsr <<<SB, 256, 0, stream>>>(binned, bcur, dinv, dinv2, csr);

    // layer 1 edges: H1 gathers -> E1
    k_agge<false><<<agge_grid, 256, 0, stream>>>(P, csr, bcur, dinv, batch, E1);
    // layer 2: relu(E1 + b1 + H1*dinv2) @ W2 -> H2 (in-place in P); edges -> E2
    k_gemm<false><<<GEMM_GRID, 256, 0, stream>>>(E1, P, W2, b1, nullptr, dinv2, batch, nullptr);
    k_agge<false><<<agge_grid, 256, 0, stream>>>(P, csr, bcur, dinv, batch, E2);
    // layer 3: relu(E2 + b2 + H2*dinv2) @ W3 -> H3; self terms -> pool; edges -> pool
    k_gemm<true ><<<GEMM_GRID, 256, 0, stream>>>(E2, P, W3, b2, b3, dinv2, batch, pool);
    k_agge<true ><<<agge_grid, 256, 0, stream>>>(P, csr, bcur, dinv, batch, pool);

    // mean + classifier
    k_cls<<<N_GRAPHS, 64, 0, stream>>>(pool, batch, Wl, bl, (float*)d_out);
}

// Round 14
// 378.363 us; speedup vs baseline: 1.1261x; 1.0260x over previous
//
#include <hip/hip_runtime.h>
#include <hip/hip_bf16.h>

#define N_NODES   100000
#define N_EDGES   1600000
#define F_IN      64
#define HID       64
#define N_CLASSES 45
#define N_GRAPHS  256
#define SB        392         // super-buckets: bucket = dst >> 8 (0..390)
#define NPB       256         // nodes per bucket
#define CAP       4608        // fixed bucket capacity; 4608 = 72*64 (mean 4082, sigma 64 -> +8s)
#define WPB       72          // waves per bucket in k_agge (CAP/64)
#define CHUNK     4096        // edges per scatter workgroup
#define NCHUNK    391         // ceil(N_EDGES / CHUNK)
#define NZB       256         // zero-blocks in the front kernel
#define GEMM_GRID 3125        // N_NODES/32
#define ZLEN4     3204096     // (E1 25.6MB + pool 64KB + E2 25.6MB) / 16

__device__ __forceinline__ float rl_f(float v, int k) {
    return __uint_as_float(__builtin_amdgcn_readlane(__float_as_uint(v), k));
}
__device__ __forceinline__ int rl_i(int v, int k) {
    return __builtin_amdgcn_readlane(v, k);
}
// fp32 <-> bf16 (RNE)
__device__ __forceinline__ unsigned short f2bf(float x) {
    unsigned u = __float_as_uint(x);
    unsigned r = u + 0x7FFFu + ((u >> 16) & 1u);
    return (unsigned short)(r >> 16);
}
__device__ __forceinline__ float bf2f(unsigned short h) {
    return __uint_as_float(((unsigned)h) << 16);
}

// ---------------- front kernel: scatter | zero(E1,pool,E2) | gemm1 ----------------
// payload: src(17b) | dstLow(8b)<<17
// LDS budget 31KB (stg 16K + bkt 8K + h/cur/off 6K + ps 1K) -> 5 blocks/CU for
// ALL branches (LDS is per-kernel; R13's 41KB stash capped gemm1 at 3 blocks/CU).
__global__ __launch_bounds__(256) void k_front(const int* __restrict__ src, const int* __restrict__ dst,
                                               int* __restrict__ bcur, int* __restrict__ binned,
                                               const float* __restrict__ x, const float* __restrict__ W1,
                                               unsigned short* __restrict__ P, float* __restrict__ zbase) {
    int bid = blockIdx.x;
    int t   = threadIdx.x;
    if (bid < NCHUNK) {
        // ---- scatter (bucket multisplit) ----
        __shared__ int stg[CHUNK];
        __shared__ unsigned short bkt[CHUNK];
        __shared__ int h[512], cur[512], off[512];
        __shared__ int ps[256];
        h[t] = 0; h[t + 256] = 0;
        __syncthreads();
        int base4 = bid * (CHUNK / 4);
        // phase 1: histogram (dst read #1)
        #pragma unroll
        for (int i = 0; i < CHUNK / 1024; i++) {
            int e4 = base4 + i * 256 + t;
            if (e4 < N_EDGES / 4) {
                int4 d = ((const int4*)dst)[e4];
                atomicAdd(&h[d.x >> 8], 1);
                atomicAdd(&h[d.y >> 8], 1);
                atomicAdd(&h[d.z >> 8], 1);
                atomicAdd(&h[d.w >> 8], 1);
            }
        }
        __syncthreads();
        // phase 2: pair-scan over 512 slots + global reservation; off = gbase - lbase
        int a0 = h[2 * t], a1 = h[2 * t + 1];
        ps[t] = a0 + a1;
        __syncthreads();
        for (int o = 1; o < 256; o <<= 1) {
            int v = (t >= o) ? ps[t - o] : 0;
            __syncthreads();
            if (t >= o) ps[t] += v;
            __syncthreads();
        }
        int pex = ps[t] - (a0 + a1);               // exclusive over pairs
        int e0 = pex, e1 = pex + a0;
        cur[2 * t] = e0; cur[2 * t + 1] = e1;
        if (2 * t < SB && a0 > 0)
            off[2 * t] = (2 * t) * CAP + atomicAdd(&bcur[2 * t], a0) - e0;
        if (2 * t + 1 < SB && a1 > 0)
            off[2 * t + 1] = (2 * t + 1) * CAP + atomicAdd(&bcur[2 * t + 1], a1) - e1;
        __syncthreads();
        int total = ps[255];                        // edges in this chunk
        // phase 3: re-read dst (+src), stage payload + bucket id
        #pragma unroll
        for (int i = 0; i < CHUNK / 1024; i++) {
            int e4 = base4 + i * 256 + t;
            if (e4 < N_EDGES / 4) {
                int4 d  = ((const int4*)dst)[e4];   // L2-hot re-read
                int4 s4 = ((const int4*)src)[e4];
                int q;
                q = atomicAdd(&cur[d.x >> 8], 1); stg[q] = s4.x | ((d.x & 255) << 17); bkt[q] = (unsigned short)(d.x >> 8);
                q = atomicAdd(&cur[d.y >> 8], 1); stg[q] = s4.y | ((d.y & 255) << 17); bkt[q] = (unsigned short)(d.y >> 8);
                q = atomicAdd(&cur[d.z >> 8], 1); stg[q] = s4.z | ((d.z & 255) << 17); bkt[q] = (unsigned short)(d.z >> 8);
                q = atomicAdd(&cur[d.w >> 8], 1); stg[q] = s4.w | ((d.w & 255) << 17); bkt[q] = (unsigned short)(d.w >> 8);
            }
        }
        __syncthreads();
        // phase 4: flat flush — coalesced LDS read, run-coalesced global write
        for (int i = t; i < total; i += 256) {
            int b = bkt[i];
            binned[off[b] + i] = stg[i];
        }
    } else if (bid < NCHUNK + NZB) {
        // ---- zero E1 | pool | E2 ----
        float4 z = make_float4(0.f, 0.f, 0.f, 0.f);
        float4* zp = (float4*)zbase;
        int zb = bid - NCHUNK;
        for (long i = (long)zb * 256 + t; i < (long)ZLEN4; i += (long)NZB * 256)
            zp[i] = z;
    } else {
        // ---- gemm1: H1 = x @ W1 (bf16) ----
        int gbid = bid - NCHUNK - NZB;
        int lane = t & 63;
        int wv   = t >> 6;
        int base = gbid * 32 + wv * 8;
        float xr[8], acc[8];
        #pragma unroll
        for (int r = 0; r < 8; r++) {
            xr[r]  = x[(size_t)(base + r) * 64 + lane];
            acc[r] = 0.f;
        }
        for (int kb = 0; kb < 64; kb += 8) {
            float wb[8];
            #pragma unroll
            for (int j = 0; j < 8; j++) wb[j] = W1[(kb + j) * 64 + lane];
            #pragma unroll
            for (int j = 0; j < 8; j++) {
                #pragma unroll
                for (int r = 0; r < 8; r++)
                    acc[r] = fmaf(rl_f(xr[r], kb + j), wb[j], acc[r]);
            }
        }
        #pragma unroll
        for (int r = 0; r < 8; r++)
            P[(size_t)(base + r) * 64 + lane] = f2bf(acc[r]);
    }
}

// ---------------- per-bucket: degrees -> dinv/dinv2 + node-sorted csr fill ----------------
__global__ __launch_bounds__(256) void k_bcsr(const int* __restrict__ binned, const int* __restrict__ bcur,
                                              float* __restrict__ dinv, float* __restrict__ dinv2,
                                              int* __restrict__ csr) {
    __shared__ int h[NPB];
    __shared__ int ts[NPB];
    int t = threadIdx.x;
    int b = blockIdx.x;
    int nb0  = b << 8;
    int ebeg = b * CAP;
    int ecnt = bcur[b]; if (ecnt > CAP) ecnt = CAP;
    h[t] = 0;
    __syncthreads();
    for (int i = t; i < ecnt; i += 256)
        atomicAdd(&h[binned[ebeg + i] >> 17], 1);
    __syncthreads();
    int c = h[t];
    ts[t] = c;
    __syncthreads();
    for (int o = 1; o < 256; o <<= 1) {
        int v = (t >= o) ? ts[t - o] : 0;
        __syncthreads();
        if (t >= o) ts[t] += v;
        __syncthreads();
    }
    int excl = ts[t] - c + ebeg;
    int n = nb0 + t;
    if (n < N_NODES) {
        float inv = 1.0f / (float)(c + 1);         // +1 self loop
        dinv2[n] = inv;
        dinv[n]  = sqrtf(inv);
    }
    __syncthreads();
    h[t] = excl;                                   // per-node write cursor
    __syncthreads();
    for (int i = t; i < ecnt; i += 256) {
        int p = binned[ebeg + i];
        int q = atomicAdd(&h[p >> 17], 1);
        csr[q] = p;                                // keep src | dstLow<<17
    }
}

// ---------------- GEMM layers 2/3 ----------------
// xin = relu(E[n] + bprev + Hprev[n]*dinv2[n]);  Hnew = xin @ W  (bf16, in-place in P)
// POOLI (layer 3): pool[batch[n]] += bcurr + Hnew[n]*dinv2[n]
template<bool POOLI>
__global__ __launch_bounds__(256) void k_gemm(const float* __restrict__ E,
                                              unsigned short* P,            // aliased in/out (row-private)
                                              const float* __restrict__ W,
                                              const float* __restrict__ bprev,
                                              const float* __restrict__ bcurr,
                                              const float* __restrict__ dinv2,
                                              const int* __restrict__ batch,
                                              float* __restrict__ pool) {
    int lane = threadIdx.x & 63;
    int wv   = threadIdx.x >> 6;
    int base = blockIdx.x * 32 + wv * 8;           // grid exact (3125*32)
    float bp = bprev[lane];
    float xr[8], acc[8];
    #pragma unroll
    for (int r = 0; r < 8; r++) {
        int n = base + r;
        float hp = bf2f(P[(size_t)n * 64 + lane]);
        float a  = E[(size_t)n * 64 + lane] + fmaf(hp, dinv2[n], bp);
        xr[r]  = fmaxf(a, 0.f);
        acc[r] = 0.f;
    }
    for (int kb = 0; kb < 64; kb += 8) {
        float wb[8];
        #pragma unroll
        for (int j = 0; j < 8; j++) wb[j] = W[(kb + j) * 64 + lane];
        #pragma unroll
        for (int j = 0; j < 8; j++) {
            #pragma unroll
            for (int r = 0; r < 8; r++)
                acc[r] = fmaf(rl_f(xr[r], kb + j), wb[j], acc[r]);
        }
    }
    #pragma unroll
    for (int r = 0; r < 8; r++)
        P[(size_t)(base + r) * 64 + lane] = f2bf(acc[r]);
    if (POOLI) {
        float bv = bcurr[lane];
        float d2[8];
        #pragma unroll
        for (int r = 0; r < 8; r++) d2[r] = dinv2[base + r];
        int g0 = batch[base], g7 = batch[base + 7];
        if (g0 == g7) {
            float s = 0.f;
            #pragma unroll
            for (int r = 0; r < 8; r++) s += fmaf(acc[r], d2[r], bv);
            atomicAdd(&pool[g0 * 64 + lane], s);
        } else {
            #pragma unroll
            for (int r = 0; r < 8; r++) {
                int g = batch[base + r];
                atomicAdd(&pool[g * 64 + lane], fmaf(acc[r], d2[r], bv));
            }
        }
    }
}

// ---------------- Edge-parallel aggregation (bf16 gather; R10 loop) ----------------
// Wave owns 64 csr slots (node-sorted runs within one bucket).
// For each dst-run: Out[dst] += dinv[dst] * sum(dinv[src]*H[src])  (atomic; Out pre-zeroed)
// POOLEP: flush into pool[batch[dst]] instead (layer 3).
template<bool POOLEP>
__global__ __launch_bounds__(256, 8) void k_agge(const unsigned short* __restrict__ Hbuf,
                                                 const int* __restrict__ csr,
                                                 const int* __restrict__ bcur,
                                                 const float* __restrict__ dinv,
                                                 const int* __restrict__ batch,
                                                 float* __restrict__ Out) {
    int wv   = threadIdx.x >> 6;
    int lane = threadIdx.x & 63;
    int wid  = blockIdx.x * 4 + wv;                // 0 .. SB*WPB-1 (grid exact)
    int b    = wid / WPB;
    int lw   = wid - b * WPB;
    int used = bcur[b]; if (used > CAP) used = CAP;
    int e0   = lw * 64;
    int rem  = used - e0;
    if (rem <= 0) return;
    if (rem > 64) rem = 64;
    int base = b * CAP + e0;

    int p = 0;
    float cv = 0.f;
    if (lane < rem) {
        p  = csr[base + lane];                     // coalesced 256B
        cv = dinv[p & 0x1FFFF];                    // lane-parallel gather, L2-hot
    }
    int sv = p & 0x1FFFF;
    int dv = p >> 17;                              // dstLow (8b)

    auto flush = [&](int dl, float a) {
        int dst = (b << 8) + dl;
        if (dst < N_NODES) {
            float val = dinv[dst] * a;             // uniform load
            if (POOLEP) {
                int g = batch[dst];                // uniform load
                atomicAdd(&Out[g * 64 + lane], val);
            } else {
                atomicAdd(&Out[(size_t)dst * 64 + lane], val);
            }
        }
    };

    int dprev = rl_i(dv, 0);
    float acc = 0.f;
    int j = 0;
    for (; j + 8 <= rem; j += 8) {
        int   s0 = rl_i(sv, j),     s1 = rl_i(sv, j + 1);
        int   s2 = rl_i(sv, j + 2), s3 = rl_i(sv, j + 3);
        int   s4 = rl_i(sv, j + 4), s5 = rl_i(sv, j + 5);
        int   s6 = rl_i(sv, j + 6), s7 = rl_i(sv, j + 7);
        float c0 = rl_f(cv, j),     c1 = rl_f(cv, j + 1);
        float c2 = rl_f(cv, j + 2), c3 = rl_f(cv, j + 3);
        float c4 = rl_f(cv, j + 4), c5 = rl_f(cv, j + 5);
        float c6 = rl_f(cv, j + 6), c7 = rl_f(cv, j + 7);
        int   d0 = rl_i(dv, j),     d1 = rl_i(dv, j + 1);
        int   d2 = rl_i(dv, j + 2), d3 = rl_i(dv, j + 3);
        int   d4 = rl_i(dv, j + 4), d5 = rl_i(dv, j + 5);
        int   d6 = rl_i(dv, j + 6), d7 = rl_i(dv, j + 7);
        unsigned short u0 = Hbuf[(size_t)s0 * 64 + lane];   // 8 gathers in flight
        unsigned short u1 = Hbuf[(size_t)s1 * 64 + lane];
        unsigned short u2 = Hbuf[(size_t)s2 * 64 + lane];
        unsigned short u3 = Hbuf[(size_t)s3 * 64 + lane];
        unsigned short u4 = Hbuf[(size_t)s4 * 64 + lane];
        unsigned short u5 = Hbuf[(size_t)s5 * 64 + lane];
        unsigned short u6 = Hbuf[(size_t)s6 * 64 + lane];
        unsigned short u7 = Hbuf[(size_t)s7 * 64 + lane];
        if (d0 != dprev) { flush(dprev, acc); acc = 0.f; dprev = d0; }
        acc = fmaf(bf2f(u0), c0, acc);
        if (d1 != dprev) { flush(dprev, acc); acc = 0.f; dprev = d1; }
        acc = fmaf(bf2f(u1), c1, acc);
        if (d2 != dprev) { flush(dprev, acc); acc = 0.f; dprev = d2; }
        acc = fmaf(bf2f(u2), c2, acc);
        if (d3 != dprev) { flush(dprev, acc); acc = 0.f; dprev = d3; }
        acc = fmaf(bf2f(u3), c3, acc);
        if (d4 != dprev) { flush(dprev, acc); acc = 0.f; dprev = d4; }
        acc = fmaf(bf2f(u4), c4, acc);
        if (d5 != dprev) { flush(dprev, acc); acc = 0.f; dprev = d5; }
        acc = fmaf(bf2f(u5), c5, acc);
        if (d6 != dprev) { flush(dprev, acc); acc = 0.f; dprev = d6; }
        acc = fmaf(bf2f(u6), c6, acc);
        if (d7 != dprev) { flush(dprev, acc); acc = 0.f; dprev = d7; }
        acc = fmaf(bf2f(u7), c7, acc);
    }
    for (; j < rem; j++) {
        int   s0 = rl_i(sv, j);
        float c0 = rl_f(cv, j);
        int   d0 = rl_i(dv, j);
        unsigned short u0 = Hbuf[(size_t)s0 * 64 + lane];
        if (d0 != dprev) { flush(dprev, acc); acc = 0.f; dprev = d0; }
        acc = fmaf(bf2f(u0), c0, acc);
    }
    flush(dprev, acc);
}

// ---------------- mean + classifier ----------------
__device__ __forceinline__ int lbound(const int* __restrict__ a, int n, int v) {
    int lo = 0, hi = n;
    while (lo < hi) { int m = (lo + hi) >> 1; if (a[m] < v) lo = m + 1; else hi = m; }
    return lo;
}

__global__ __launch_bounds__(64) void k_cls(const float* __restrict__ pool, const int* __restrict__ batch,
                                            const float* __restrict__ Wl, const float* __restrict__ bl,
                                            float* __restrict__ out) {
    __shared__ float pm[64];
    __shared__ int bounds[2];
    int g = blockIdx.x;
    int t = threadIdx.x;
    if (t < 2) bounds[t] = lbound(batch, N_NODES, g + t);
    __syncthreads();
    float cnt = (float)(bounds[1] - bounds[0]);
    pm[t] = pool[g * 64 + t] / fmaxf(cnt, 1.0f);
    __syncthreads();
    if (t < N_CLASSES) {
        float o = bl[t];
        #pragma unroll
        for (int k = 0; k < HID; k++) o = fmaf(pm[k], Wl[k * N_CLASSES + t], o);
        out[g * N_CLASSES + t] = o;
    }
}

// ---------------- launch ----------------

extern "C" void kernel_launch(void* const* d_in, const int* in_sizes, int n_in,
                              void* d_out, int out_size, void* d_ws, size_t ws_size,
                              hipStream_t stream) {
    const float* x     = (const float*)d_in[0];
    const int*   eidx  = (const int*)  d_in[1];
    const int*   batch = (const int*)  d_in[2];
    const float* W1 = (const float*)d_in[3];
    const float* b1 = (const float*)d_in[4];
    const float* W2 = (const float*)d_in[5];
    const float* b2 = (const float*)d_in[6];
    const float* W3 = (const float*)d_in[7];
    const float* b3 = (const float*)d_in[8];
    const float* Wl = (const float*)d_in[9];
    const float* bl = (const float*)d_in[10];
    const int* src = eidx;
    const int* dst = eidx + N_EDGES;

    char* p = (char*)d_ws;
    auto alloc = [&](size_t bytes) -> void* {
        void* r = (void*)p;
        p += (bytes + 255) & ~(size_t)255;
        return r;
    };
    float* dinv  = (float*)alloc((size_t)N_NODES * 4);
    float* dinv2 = (float*)alloc((size_t)N_NODES * 4);
    int*   csr   = (int*)  alloc((size_t)SB * CAP * 4);
    unsigned short* P = (unsigned short*)alloc((size_t)N_NODES * 64 * 2);  // bf16 H
    float* E1    = (float*)alloc((size_t)N_NODES * 64 * 4);   // edge sums L1 (zeroed span start)
    float* pool  = (float*)alloc((size_t)N_GRAPHS * 64 * 4);  // contiguous after E1
    float* E2    = (float*)alloc((size_t)N_NODES * 64 * 4);   // contiguous after pool
    int*   bcur  = (int*)  alloc((size_t)SB * 4);
    int*   binned = (int*) alloc((size_t)SB * CAP * 4);

    const int agge_grid  = SB * WPB / 4;           // 7056, exact
    const int front_grid = NCHUNK + NZB + GEMM_GRID;

    // ---- front: scatter | zero(E1,pool,E2) | gemm1 (all independent) ----
    hipMemsetAsync(bcur, 0, (size_t)SB * 4, stream);
    k_front<<<front_grid, 256, 0, stream>>>(src, dst, bcur, binned, x, W1, P, E1);
    k_bcsr <<<SB, 256, 0, stream>>>(binned, bcur, dinv, dinv2, csr);

    // layer 1 edges: H1 gathers -> E1
    k_agge<false><<<agge_grid, 256, 0, stream>>>(P, csr, bcur, dinv, batch, E1);
    // layer 2: relu(E1 + b1 + H1*dinv2) @ W2 -> H2 (in-place in P); edges -> E2
    k_gemm<false><<<GEMM_GRID, 256, 0, stream>>>(E1, P, W2, b1, nullptr, dinv2, batch, nullptr);
    k_agge<false><<<agge_grid, 256, 0, stream>>>(P, csr, bcur, dinv, batch, E2);
    // layer 3: relu(E2 + b2 + H2*dinv2) @ W3 -> H3; self terms -> pool; edges -> pool
    k_gemm<true ><<<GEMM_GRID, 256, 0, stream>>>(E2, P, W3, b2, b3, dinv2, batch, pool);
    k_agge<true ><<<agge_grid, 256, 0, stream>>>(P, csr, bcur, dinv, batch, pool);

    // mean + classifier
    k_cls<<<N_GRAPHS, 64, 0, stream>>>(pool, batch, Wl, bl, (float*)d_out);
}

// Round 15
// 369.814 us; speedup vs baseline: 1.1521x; 1.0231x over previous
//
#include <hip/hip_runtime.h>
#include <hip/hip_bf16.h>

#define N_NODES   100000
#define N_EDGES   1600000
#define F_IN      64
#define HID       64
#define N_CLASSES 45
#define N_GRAPHS  256
#define SB        392         // super-buckets: bucket = dst >> 8 (0..390)
#define NPB       256         // nodes per bucket
#define CAP       4608        // fixed bucket capacity; 4608 = 72*64 (mean 4082, sigma 64 -> +8s)
#define WPB       72          // waves per bucket in k_agge (CAP/64)
#define CHUNK     4096        // edges per scatter workgroup
#define NCHUNK    391         // ceil(N_EDGES / CHUNK)
#define NZB       192         // zero-blocks in the front kernel (E1 only)
#define GEMM_GRID 3125        // N_NODES/32
#define AGGE_GRID 7056        // SB*WPB/4
#define NZB2      192         // zero-role blocks appended to agge1 (pool+E2)
#define ZLEN4_F   1600000     // E1 bytes/16  (25.6 MB)
#define ZLEN4_A   1604096     // (pool 64KB + E2 25.6MB)/16

__device__ __forceinline__ float rl_f(float v, int k) {
    return __uint_as_float(__builtin_amdgcn_readlane(__float_as_uint(v), k));
}
__device__ __forceinline__ int rl_i(int v, int k) {
    return __builtin_amdgcn_readlane(v, k);
}
// fp32 <-> bf16 (RNE)
__device__ __forceinline__ unsigned short f2bf(float x) {
    unsigned u = __float_as_uint(x);
    unsigned r = u + 0x7FFFu + ((u >> 16) & 1u);
    return (unsigned short)(r >> 16);
}
__device__ __forceinline__ float bf2f(unsigned short h) {
    return __uint_as_float(((unsigned)h) << 16);
}

// ---------------- front kernel: scatter | zero(E1) | gemm1 ----------------
// payload: src(17b) | dstLow(8b)<<17
__global__ __launch_bounds__(256) void k_front(const int* __restrict__ src, const int* __restrict__ dst,
                                               int* __restrict__ bcur, int* __restrict__ binned,
                                               const float* __restrict__ x, const float* __restrict__ W1,
                                               unsigned short* __restrict__ P, float* __restrict__ zbase) {
    int bid = blockIdx.x;
    int t   = threadIdx.x;
    if (bid < NCHUNK) {
        // ---- scatter (bucket multisplit) ----
        __shared__ int stg[CHUNK];
        __shared__ unsigned short bkt[CHUNK];
        __shared__ int h[512], cur[512], off[512];
        __shared__ int ps[256];
        h[t] = 0; h[t + 256] = 0;
        __syncthreads();
        int base4 = bid * (CHUNK / 4);
        // phase 1: histogram (dst read #1)
        #pragma unroll
        for (int i = 0; i < CHUNK / 1024; i++) {
            int e4 = base4 + i * 256 + t;
            if (e4 < N_EDGES / 4) {
                int4 d = ((const int4*)dst)[e4];
                atomicAdd(&h[d.x >> 8], 1);
                atomicAdd(&h[d.y >> 8], 1);
                atomicAdd(&h[d.z >> 8], 1);
                atomicAdd(&h[d.w >> 8], 1);
            }
        }
        __syncthreads();
        // phase 2: pair-scan over 512 slots + global reservation; off = gbase - lbase
        int a0 = h[2 * t], a1 = h[2 * t + 1];
        ps[t] = a0 + a1;
        __syncthreads();
        for (int o = 1; o < 256; o <<= 1) {
            int v = (t >= o) ? ps[t - o] : 0;
            __syncthreads();
            if (t >= o) ps[t] += v;
            __syncthreads();
        }
        int pex = ps[t] - (a0 + a1);               // exclusive over pairs
        int e0 = pex, e1 = pex + a0;
        cur[2 * t] = e0; cur[2 * t + 1] = e1;
        if (2 * t < SB && a0 > 0)
            off[2 * t] = (2 * t) * CAP + atomicAdd(&bcur[2 * t], a0) - e0;
        if (2 * t + 1 < SB && a1 > 0)
            off[2 * t + 1] = (2 * t + 1) * CAP + atomicAdd(&bcur[2 * t + 1], a1) - e1;
        __syncthreads();
        int total = ps[255];                        // edges in this chunk
        // phase 3: re-read dst (+src), stage payload + bucket id
        #pragma unroll
        for (int i = 0; i < CHUNK / 1024; i++) {
            int e4 = base4 + i * 256 + t;
            if (e4 < N_EDGES / 4) {
                int4 d  = ((const int4*)dst)[e4];   // L2-hot re-read
                int4 s4 = ((const int4*)src)[e4];
                int q;
                q = atomicAdd(&cur[d.x >> 8], 1); stg[q] = s4.x | ((d.x & 255) << 17); bkt[q] = (unsigned short)(d.x >> 8);
                q = atomicAdd(&cur[d.y >> 8], 1); stg[q] = s4.y | ((d.y & 255) << 17); bkt[q] = (unsigned short)(d.y >> 8);
                q = atomicAdd(&cur[d.z >> 8], 1); stg[q] = s4.z | ((d.z & 255) << 17); bkt[q] = (unsigned short)(d.z >> 8);
                q = atomicAdd(&cur[d.w >> 8], 1); stg[q] = s4.w | ((d.w & 255) << 17); bkt[q] = (unsigned short)(d.w >> 8);
            }
        }
        __syncthreads();
        // phase 4: flat flush — coalesced LDS read, run-coalesced global write
        for (int i = t; i < total; i += 256) {
            int b = bkt[i];
            binned[off[b] + i] = stg[i];
        }
    } else if (bid < NCHUNK + NZB) {
        // ---- zero E1 ----
        float4 z = make_float4(0.f, 0.f, 0.f, 0.f);
        float4* zp = (float4*)zbase;
        int zb = bid - NCHUNK;
        for (long i = (long)zb * 256 + t; i < (long)ZLEN4_F; i += (long)NZB * 256)
            zp[i] = z;
    } else {
        // ---- gemm1: H1 = x @ W1 (bf16) ----
        int gbid = bid - NCHUNK - NZB;
        int lane = t & 63;
        int wv   = t >> 6;
        int base = gbid * 32 + wv * 8;
        float xr[8], acc[8];
        #pragma unroll
        for (int r = 0; r < 8; r++) {
            xr[r]  = x[(size_t)(base + r) * 64 + lane];
            acc[r] = 0.f;
        }
        for (int kb = 0; kb < 64; kb += 8) {
            float wb[8];
            #pragma unroll
            for (int j = 0; j < 8; j++) wb[j] = W1[(kb + j) * 64 + lane];
            #pragma unroll
            for (int j = 0; j < 8; j++) {
                #pragma unroll
                for (int r = 0; r < 8; r++)
                    acc[r] = fmaf(rl_f(xr[r], kb + j), wb[j], acc[r]);
            }
        }
        #pragma unroll
        for (int r = 0; r < 8; r++)
            P[(size_t)(base + r) * 64 + lane] = f2bf(acc[r]);
    }
}

// ---------------- per-bucket: degrees -> dinv/dinv2 + node-sorted csr fill ----------------
__global__ __launch_bounds__(256) void k_bcsr(const int* __restrict__ binned, const int* __restrict__ bcur,
                                              float* __restrict__ dinv, float* __restrict__ dinv2,
                                              int* __restrict__ csr) {
    __shared__ int h[NPB];
    __shared__ int ts[NPB];
    int t = threadIdx.x;
    int b = blockIdx.x;
    int nb0  = b << 8;
    int ebeg = b * CAP;
    int ecnt = bcur[b]; if (ecnt > CAP) ecnt = CAP;
    h[t] = 0;
    __syncthreads();
    for (int i = t; i < ecnt; i += 256)
        atomicAdd(&h[binned[ebeg + i] >> 17], 1);
    __syncthreads();
    int c = h[t];
    ts[t] = c;
    __syncthreads();
    for (int o = 1; o < 256; o <<= 1) {
        int v = (t >= o) ? ts[t - o] : 0;
        __syncthreads();
        if (t >= o) ts[t] += v;
        __syncthreads();
    }
    int excl = ts[t] - c + ebeg;
    int n = nb0 + t;
    if (n < N_NODES) {
        float inv = 1.0f / (float)(c + 1);         // +1 self loop
        dinv2[n] = inv;
        dinv[n]  = sqrtf(inv);
    }
    __syncthreads();
    h[t] = excl;                                   // per-node write cursor
    __syncthreads();
    for (int i = t; i < ecnt; i += 256) {
        int p = binned[ebeg + i];
        int q = atomicAdd(&h[p >> 17], 1);
        csr[q] = p;                                // keep src | dstLow<<17
    }
}

// ---------------- GEMM layers 2/3 ----------------
// xin = relu(E[n] + bprev + Hprev[n]*dinv2[n]);  Hnew = xin @ W  (bf16, in-place in P)
// POOLI (layer 3): pool[batch[n]] += bcurr + Hnew[n]*dinv2[n]
template<bool POOLI>
__global__ __launch_bounds__(256) void k_gemm(const float* __restrict__ E,
                                              unsigned short* P,            // aliased in/out (row-private)
                                              const float* __restrict__ W,
                                              const float* __restrict__ bprev,
                                              const float* __restrict__ bcurr,
                                              const float* __restrict__ dinv2,
                                              const int* __restrict__ batch,
                                              float* __restrict__ pool) {
    int lane = threadIdx.x & 63;
    int wv   = threadIdx.x >> 6;
    int base = blockIdx.x * 32 + wv * 8;           // grid exact (3125*32)
    float bp = bprev[lane];
    float xr[8], acc[8];
    #pragma unroll
    for (int r = 0; r < 8; r++) {
        int n = base + r;
        float hp = bf2f(P[(size_t)n * 64 + lane]);
        float a  = E[(size_t)n * 64 + lane] + fmaf(hp, dinv2[n], bp);
        xr[r]  = fmaxf(a, 0.f);
        acc[r] = 0.f;
    }
    for (int kb = 0; kb < 64; kb += 8) {
        float wb[8];
        #pragma unroll
        for (int j = 0; j < 8; j++) wb[j] = W[(kb + j) * 64 + lane];
        #pragma unroll
        for (int j = 0; j < 8; j++) {
            #pragma unroll
            for (int r = 0; r < 8; r++)
                acc[r] = fmaf(rl_f(xr[r], kb + j), wb[j], acc[r]);
        }
    }
    #pragma unroll
    for (int r = 0; r < 8; r++)
        P[(size_t)(base + r) * 64 + lane] = f2bf(acc[r]);
    if (POOLI) {
        float bv = bcurr[lane];
        float d2[8];
        #pragma unroll
        for (int r = 0; r < 8; r++) d2[r] = dinv2[base + r];
        int g0 = batch[base], g7 = batch[base + 7];
        if (g0 == g7) {
            float s = 0.f;
            #pragma unroll
            for (int r = 0; r < 8; r++) s += fmaf(acc[r], d2[r], bv);
            atomicAdd(&pool[g0 * 64 + lane], s);
        } else {
            #pragma unroll
            for (int r = 0; r < 8; r++) {
                int g = batch[base + r];
                atomicAdd(&pool[g * 64 + lane], fmaf(acc[r], d2[r], bv));
            }
        }
    }
}

// ---------------- Edge-parallel aggregation (bf16 gather; depth-16) ----------------
// Wave owns 64 csr slots (node-sorted runs within one bucket).
// For each dst-run: Out[dst] += dinv[dst] * sum(dinv[src]*H[src])  (atomic; Out pre-zeroed)
// POOLEP: flush into pool[batch[dst]] instead (layer 3).
// ZROLE: trailing NZB2 blocks zero the pool|E2 span (rides agge1's latency shadow).
template<bool POOLEP, bool ZROLE>
__global__ __launch_bounds__(256, 8) void k_agge(const unsigned short* __restrict__ Hbuf,
                                                 const int* __restrict__ csr,
                                                 const int* __restrict__ bcur,
                                                 const float* __restrict__ dinv,
                                                 const int* __restrict__ batch,
                                                 float* __restrict__ Out,
                                                 float* __restrict__ zbase) {
    int t = threadIdx.x;
    if (ZROLE && blockIdx.x >= AGGE_GRID) {
        float4 z = make_float4(0.f, 0.f, 0.f, 0.f);
        float4* zp = (float4*)zbase;
        int zb = blockIdx.x - AGGE_GRID;
        for (long i = (long)zb * 256 + t; i < (long)ZLEN4_A; i += (long)NZB2 * 256)
            zp[i] = z;
        return;
    }
    int wv   = t >> 6;
    int lane = t & 63;
    int wid  = blockIdx.x * 4 + wv;                // 0 .. SB*WPB-1
    int b    = wid / WPB;
    int lw   = wid - b * WPB;
    int used = bcur[b]; if (used > CAP) used = CAP;
    int e0   = lw * 64;
    int rem  = used - e0;
    if (rem <= 0) return;
    if (rem > 64) rem = 64;
    int base = b * CAP + e0;

    int p = 0;
    float cv = 0.f;
    if (lane < rem) {
        p  = csr[base + lane];                     // coalesced 256B
        cv = dinv[p & 0x1FFFF];                    // lane-parallel gather, L2-hot
    }
    int sv = p & 0x1FFFF;
    int dv = p >> 17;                              // dstLow (8b)

    auto flush = [&](int dl, float a) {
        int dst = (b << 8) + dl;
        if (dst < N_NODES) {
            float val = dinv[dst] * a;             // uniform load
            if (POOLEP) {
                int g = batch[dst];                // uniform load
                atomicAdd(&Out[g * 64 + lane], val);
            } else {
                atomicAdd(&Out[(size_t)dst * 64 + lane], val);
            }
        }
    };

    int dprev = rl_i(dv, 0);
    float acc = 0.f;
    int j = 0;
    for (; j + 16 <= rem; j += 16) {
        unsigned short u[16];
        #pragma unroll
        for (int i = 0; i < 16; i++) {             // 16 gathers issued up front
            int s = rl_i(sv, j + i);
            u[i] = Hbuf[(size_t)s * 64 + lane];
        }
        #pragma unroll
        for (int i = 0; i < 16; i++) {
            int   d = rl_i(dv, j + i);
            float c = rl_f(cv, j + i);
            if (d != dprev) { flush(dprev, acc); acc = 0.f; dprev = d; }
            acc = fmaf(bf2f(u[i]), c, acc);
        }
    }
    for (; j < rem; j++) {
        int   s0 = rl_i(sv, j);
        float c0 = rl_f(cv, j);
        int   d0 = rl_i(dv, j);
        unsigned short u0 = Hbuf[(size_t)s0 * 64 + lane];
        if (d0 != dprev) { flush(dprev, acc); acc = 0.f; dprev = d0; }
        acc = fmaf(bf2f(u0), c0, acc);
    }
    flush(dprev, acc);
}

// ---------------- mean + classifier ----------------
__device__ __forceinline__ int lbound(const int* __restrict__ a, int n, int v) {
    int lo = 0, hi = n;
    while (lo < hi) { int m = (lo + hi) >> 1; if (a[m] < v) lo = m + 1; else hi = m; }
    return lo;
}

__global__ __launch_bounds__(64) void k_cls(const float* __restrict__ pool, const int* __restrict__ batch,
                                            const float* __restrict__ Wl, const float* __restrict__ bl,
                                            float* __restrict__ out) {
    __shared__ float pm[64];
    __shared__ int bounds[2];
    int g = blockIdx.x;
    int t = threadIdx.x;
    if (t < 2) bounds[t] = lbound(batch, N_NODES, g + t);
    __syncthreads();
    float cnt = (float)(bounds[1] - bounds[0]);
    pm[t] = pool[g * 64 + t] / fmaxf(cnt, 1.0f);
    __syncthreads();
    if (t < N_CLASSES) {
        float o = bl[t];
        #pragma unroll
        for (int k = 0; k < HID; k++) o = fmaf(pm[k], Wl[k * N_CLASSES + t], o);
        out[g * N_CLASSES + t] = o;
    }
}

// ---------------- launch ----------------

extern "C" void kernel_launch(void* const* d_in, const int* in_sizes, int n_in,
                              void* d_out, int out_size, void* d_ws, size_t ws_size,
                              hipStream_t stream) {
    const float* x     = (const float*)d_in[0];
    const int*   eidx  = (const int*)  d_in[1];
    const int*   batch = (const int*)  d_in[2];
    const float* W1 = (const float*)d_in[3];
    const float* b1 = (const float*)d_in[4];
    const float* W2 = (const float*)d_in[5];
    const float* b2 = (const float*)d_in[6];
    const float* W3 = (const float*)d_in[7];
    const float* b3 = (const float*)d_in[8];
    const float* Wl = (const float*)d_in[9];
    const float* bl = (const float*)d_in[10];
    const int* src = eidx;
    const int* dst = eidx + N_EDGES;

    char* p = (char*)d_ws;
    auto alloc = [&](size_t bytes) -> void* {
        void* r = (void*)p;
        p += (bytes + 255) & ~(size_t)255;
        return r;
    };
    float* dinv  = (float*)alloc((size_t)N_NODES * 4);
    float* dinv2 = (float*)alloc((size_t)N_NODES * 4);
    int*   csr   = (int*)  alloc((size_t)SB * CAP * 4);
    unsigned short* P = (unsigned short*)alloc((size_t)N_NODES * 64 * 2);  // bf16 H
    float* E1    = (float*)alloc((size_t)N_NODES * 64 * 4);   // edge sums L1
    float* pool  = (float*)alloc((size_t)N_GRAPHS * 64 * 4);  // contiguous after E1
    float* E2    = (float*)alloc((size_t)N_NODES * 64 * 4);   // contiguous after pool
    int*   bcur  = (int*)  alloc((size_t)SB * 4);
    int*   binned = (int*) alloc((size_t)SB * CAP * 4);

    const int front_grid = NCHUNK + NZB + GEMM_GRID;

    // ---- front: scatter | zero(E1) | gemm1 (all independent) ----
    hipMemsetAsync(bcur, 0, (size_t)SB * 4, stream);
    k_front<<<front_grid, 256, 0, stream>>>(src, dst, bcur, binned, x, W1, P, E1);
    k_bcsr <<<SB, 256, 0, stream>>>(binned, bcur, dinv, dinv2, csr);

    // layer 1 edges: H1 gathers -> E1 ; trailing blocks zero pool|E2
    k_agge<false, true ><<<AGGE_GRID + NZB2, 256, 0, stream>>>(P, csr, bcur, dinv, batch, E1, pool);
    // layer 2: relu(E1 + b1 + H1*dinv2) @ W2 -> H2 (in-place in P); edges -> E2
    k_gemm<false><<<GEMM_GRID, 256, 0, stream>>>(E1, P, W2, b1, nullptr, dinv2, batch, nullptr);
    k_agge<false, false><<<AGGE_GRID, 256, 0, stream>>>(P, csr, bcur, dinv, batch, E2, nullptr);
    // layer 3: relu(E2 + b2 + H2*dinv2) @ W3 -> H3; self terms -> pool; edges -> pool
    k_gemm<true ><<<GEMM_GRID, 256, 0, stream>>>(E2, P, W3, b2, b3, dinv2, batch, pool);
    k_agge<true , false><<<AGGE_GRID, 256, 0, stream>>>(P, csr, bcur, dinv, batch, pool, nullptr);

    // mean + classifier
    k_cls<<<N_GRAPHS, 64, 0, stream>>>(pool, batch, Wl, bl, (float*)d_out);
}